// Round 6
// baseline (252.504 us; speedup 1.0000x reference)
//
#include <hip/hip_runtime.h>
#include <stdint.h>
#include <stddef.h>

#define DIM 1024
#define EPS 1e-8f

typedef __attribute__((ext_vector_type(4)))  int   i32x4;
typedef __attribute__((ext_vector_type(8)))  int   i32x8;
typedef __attribute__((ext_vector_type(4)))  float f32x4;

// e8m0 scale byte 123 = 2^(123-127) = 1/16 per operand -> 1/256 on the product,
// exactly cancelling the x16 prep scaling (bit-exact pow2 exponent shift).
#define SCALE8 0x7B7B7B7B

// async global->LDS, 16B per lane, wave-uniform LDS base + lane*16
__device__ __forceinline__ void async_copy16(const void* g, void* l) {
    __builtin_amdgcn_global_load_lds(
        (__attribute__((address_space(1))) void*)const_cast<void*>(g),
        (__attribute__((address_space(3))) void*)(l), 16, 0, 0);
}

// ---------------------------------------------------------------------------
// Prep: wave-per-row. Unit-normalize, scale by 16 (undone by hw e8m0 scales in
// the GEMM), cast to OCP fp8 e4m3, store rows LINEARLY with coalesced dword
// stores. The GEMM's staging-side chunk XOR supplies the LDS bank swizzle.
// ---------------------------------------------------------------------------
__global__ __launch_bounds__(256)
void prep_all(const float* __restrict__ x, const float* __restrict__ pos,
              const float* __restrict__ neg,
              unsigned char* __restrict__ Xn, unsigned char* __restrict__ Nn,
              float* __restrict__ simOut, float* __restrict__ rowsum, int bn) {
    const int lane = threadIdx.x & 63;
    const int wave = threadIdx.x >> 6;
    const int grow = blockIdx.x * 4 + wave;
    const bool isX = grow < bn;
    const int row  = isX ? grow : grow - bn;
    const float* src = isX ? x : neg;
    unsigned char* dst = isX ? Xn : Nn;

    const float4* s = (const float4*)(src + (size_t)row * DIM);
    float4 xv[4], pv[4];
    float sxx = 0.f, spp = 0.f, sxp = 0.f;
#pragma unroll
    for (int i = 0; i < 4; i++) {
        xv[i] = s[lane + 64 * i];
        sxx += xv[i].x * xv[i].x + xv[i].y * xv[i].y + xv[i].z * xv[i].z + xv[i].w * xv[i].w;
    }
    if (isX) {
        const float4* p = (const float4*)(pos + (size_t)row * DIM);
#pragma unroll
        for (int i = 0; i < 4; i++) {
            pv[i] = p[lane + 64 * i];
            spp += pv[i].x * pv[i].x + pv[i].y * pv[i].y + pv[i].z * pv[i].z + pv[i].w * pv[i].w;
            sxp += xv[i].x * pv[i].x + xv[i].y * pv[i].y + xv[i].z * pv[i].z + xv[i].w * pv[i].w;
        }
#pragma unroll
        for (int off = 1; off < 64; off <<= 1) {
            sxx += __shfl_xor(sxx, off);
            spp += __shfl_xor(spp, off);
            sxp += __shfl_xor(sxp, off);
        }
    } else {
#pragma unroll
        for (int off = 1; off < 64; off <<= 1) sxx += __shfl_xor(sxx, off);
    }
    const float nx  = sqrtf(sxx);
    const float inv = (nx > 0.f) ? (16.f / nx) : 0.f;   // x16 -> e4m3 sweet spot
    if (isX && lane == 0) {
        const float np = sqrtf(spp);
        simOut[row] = sxp / fmaxf(nx * np, EPS);
        rowsum[row] = 0.f;
    }
    unsigned int t;
    t = __builtin_amdgcn_cvt_pk_fp8_f32(xv[0].x * inv, xv[0].y * inv, 0, false);
    unsigned int q0 = __builtin_amdgcn_cvt_pk_fp8_f32(xv[0].z * inv, xv[0].w * inv, t, true);
    t = __builtin_amdgcn_cvt_pk_fp8_f32(xv[1].x * inv, xv[1].y * inv, 0, false);
    unsigned int q1 = __builtin_amdgcn_cvt_pk_fp8_f32(xv[1].z * inv, xv[1].w * inv, t, true);
    t = __builtin_amdgcn_cvt_pk_fp8_f32(xv[2].x * inv, xv[2].y * inv, 0, false);
    unsigned int q2 = __builtin_amdgcn_cvt_pk_fp8_f32(xv[2].z * inv, xv[2].w * inv, t, true);
    t = __builtin_amdgcn_cvt_pk_fp8_f32(xv[3].x * inv, xv[3].y * inv, 0, false);
    unsigned int q3 = __builtin_amdgcn_cvt_pk_fp8_f32(xv[3].z * inv, xv[3].w * inv, t, true);

    unsigned int* wr = (unsigned int*)(dst + (size_t)row * DIM);
    wr[lane]       = q0;
    wr[lane + 64]  = q1;
    wr[lane + 128] = q2;
    wr[lane + 192] = q3;
}

// ---------------------------------------------------------------------------
// Fused MX-fp8 GEMM: rowsum[i] += sum_j exp( unit(x_i) . unit(neg_j) )
// Cell: mfma_scale_f32_16x16x128_f8f6f4 ONLY (R3/R4-verified; the 32x32x64
// cell measured 4-10x slower per FLOP across three schedules R1/R2/R5).
// 256x256 tile, 8 waves (2m x 4n), per-wave 128x64 = 8mi x 4ni frags.
// Read:MFMA ratio 12:32 (was 8:16) -> per window per CU: LDS ~1660 cy vs
// MFMA 2208 cy/SIMD — MFMA-bound for the first time (R4 was 93% LDS-port).
// BK=128-B k-window (8 windows), TWO-buffer rotation (128 KB dyn LDS),
// stage-at-window-top -> compute (~2200 cy) -> drain vmcnt(0)+barrier:
// the drain exposes ~0 latency because issue precedes it by the whole
// compute phase (T14 issue-early/consume-late; R3's stall was issue->wait
// with nothing between).
// Buffer hazard: window w stages buf (w+1)&1 while reading buf w&1; the
// boundary barrier is crossed only after each wave's last MFMA consumed its
// reads (compiler lgkm waits), so next window's overwrite of buf w&1 is safe.
// LDS swizzle (R3/R4-verified): 128-B row = 8 chunks of 16 B; slot p of row
// r holds logical chunk p ^ (r&7). Staging: lane -> (srow=lane>>3,
// slot=lane&7), global chunk = slot ^ srow, glds dest linear. Read: lane
// row=l&15, q=l>>4 owns k-bytes [32q,32q+32) via b128 at slot (2q)^(r&7)
// and that ^1 (byte ^16).
// ---------------------------------------------------------------------------
__global__ __launch_bounds__(512, 2)
void gemm_exp_rowsum(const unsigned char* __restrict__ Xn,
                     const unsigned char* __restrict__ Nn,
                     float* __restrict__ rowsum) {
    constexpr int KB   = DIM;            // 1024 bytes per fp8 row
    constexpr int BK   = 128;            // bytes per k-window (K=128 elems)
    constexpr int BOFF = 256 * BK;       // B area offset within a buffer (32 KB)
    constexpr int BUFB = 2 * BOFF;       // 64 KB per buffer (A then B)
    extern __shared__ unsigned char smem[];     // 2 * BUFB = 128 KB

    const int tid  = threadIdx.x;
    const int lane = tid & 63;
    const int wave = tid >> 6;                 // 0..7

    // T1: bijective chunked XCD swizzle (nwg = 512, divisible by 8)
    const int nwg  = gridDim.x * gridDim.y;
    const int bid  = blockIdx.y * gridDim.x + blockIdx.x;
    const int swz  = (bid & 7) * (nwg >> 3) + (bid >> 3);
    const int rowBase = (swz / gridDim.x) * 256;
    const int colBase = (swz % gridDim.x) * 256;

    // staging: one glds = 1 KB = 8 rows x 128 B; wave stages A rows
    // [wave*32,+32) and B rows [wave*32,+32): 4+4 glds per window.
    const int srow = lane >> 3;                 // 0..7
    const int sch  = (lane & 7) ^ srow;         // global-side swizzle
    const unsigned char* gA = Xn + (size_t)(rowBase + wave * 32 + srow) * KB + sch * 16;
    const unsigned char* gB = Nn + (size_t)(colBase + wave * 32 + srow) * KB + sch * 16;

    const f32x4 fz = {0.f, 0.f, 0.f, 0.f};
    f32x4 acc[8][4];
#pragma unroll
    for (int mi = 0; mi < 8; mi++)
#pragma unroll
        for (int ni = 0; ni < 4; ni++) acc[mi][ni] = fz;

    const int m0   = (wave >> 2) * 128;  // M-half: 0,128
    const int n0   = (wave & 3) * 64;    // N-quarter: 0,64,128,192
    const int mrow = lane & 15;          // fragment row
    const int q    = lane >> 4;          // k-quarter: bytes [32q, 32q+32)
    const int c0   = ((2 * q) ^ (mrow & 7)) << 4;   // 2nd b128 at ^16

    int aoff[8], boff[4];
#pragma unroll
    for (int i = 0; i < 8; i++) aoff[i] = (m0 + 16 * i + mrow) * BK + c0;
#pragma unroll
    for (int i = 0; i < 4; i++) boff[i] = BOFF + (n0 + 16 * i + mrow) * BK + c0;

#define STAGE(buf, stg)                                                        \
    do {                                                                       \
        const int kq = (stg) * BK;                                             \
        unsigned char* Lb = smem + (buf) * BUFB;                               \
        _Pragma("unroll")                                                      \
        for (int i = 0; i < 4; i++) {                                          \
            async_copy16(gA + (size_t)(8 * i) * KB + kq,                       \
                         Lb + (wave * 32 + 8 * i) * BK);                       \
            async_copy16(gB + (size_t)(8 * i) * KB + kq,                       \
                         Lb + BOFF + (wave * 32 + 8 * i) * BK);                \
        }                                                                      \
    } while (0)

#define RD(base, off, dst)                                                     \
    do {                                                                       \
        i32x4 lo_ = *(const i32x4*)((base) + (off));                           \
        i32x4 hi_ = *(const i32x4*)((base) + ((off) ^ 16));                    \
        dst = __builtin_shufflevector(lo_, hi_, 0, 1, 2, 3, 4, 5, 6, 7);       \
    } while (0)

    // prologue: window 0 staged and drained (nothing to overlap yet).
    STAGE(0, 0);
    asm volatile("s_waitcnt vmcnt(0)\n\ts_barrier" ::: "memory");

#pragma unroll
    for (int w = 0; w < 8; w++) {
        const unsigned char* Ab = smem + (w & 1) * BUFB;
        if (w < 7) STAGE((w + 1) & 1, w + 1);   // issue early: hides under compute
        i32x8 Bf[4];
#pragma unroll
        for (int i = 0; i < 4; i++) RD(Ab, boff[i], Bf[i]);
#pragma unroll
        for (int mi = 0; mi < 8; mi++) {
            i32x8 Af;
            RD(Ab, aoff[mi], Af);
            __builtin_amdgcn_s_setprio(1);
#pragma unroll
            for (int ni = 0; ni < 4; ni++)
                acc[mi][ni] = __builtin_amdgcn_mfma_scale_f32_16x16x128_f8f6f4(
                    Af, Bf[ni], acc[mi][ni], 0, 0, 0, SCALE8, 0, SCALE8);
            __builtin_amdgcn_s_setprio(0);
        }
        // boundary: drain the loads issued at THIS window's top (~full
        // compute phase ago -> ~zero exposed latency), then barrier.
        if (w < 7)
            asm volatile("s_waitcnt vmcnt(0)\n\ts_barrier" ::: "memory");
    }
#undef STAGE
#undef RD

    // epilogue (R3/R4-verified): 16x16 C/D layout col=lane&15, row=q*4+reg.
    // exp, sum 4 ni blocks, 16-col shuffle reduce, 4 atomics per q-lane.
#pragma unroll
    for (int mi = 0; mi < 8; mi++) {
        float rs0 = 0.f, rs1 = 0.f, rs2 = 0.f, rs3 = 0.f;
#pragma unroll
        for (int ni = 0; ni < 4; ni++) {
            rs0 += __expf(acc[mi][ni].x);
            rs1 += __expf(acc[mi][ni].y);
            rs2 += __expf(acc[mi][ni].z);
            rs3 += __expf(acc[mi][ni].w);
        }
#pragma unroll
        for (int off = 1; off < 16; off <<= 1) {
            rs0 += __shfl_xor(rs0, off);
            rs1 += __shfl_xor(rs1, off);
            rs2 += __shfl_xor(rs2, off);
            rs3 += __shfl_xor(rs3, off);
        }
        if ((lane & 15) == 0) {
            const int r = rowBase + m0 + mi * 16 + q * 4;
            atomicAdd(&rowsum[r + 0], rs0);
            atomicAdd(&rowsum[r + 1], rs1);
            atomicAdd(&rowsum[r + 2], rs2);
            atomicAdd(&rowsum[r + 3], rs3);
        }
    }
}

__global__ __launch_bounds__(1024)
void loss_kernel(const float* __restrict__ rowsum, const float* __restrict__ sim,
                 float* __restrict__ out, int bn) {
    const int tid  = threadIdx.x;
    const int lane = tid & 63;
    const int wave = tid >> 6;
    float acc = 0.f;
    for (int i = tid; i < bn; i += 1024) acc += logf(rowsum[i]) - sim[i];
#pragma unroll
    for (int off = 1; off < 64; off <<= 1) acc += __shfl_xor(acc, off);
    __shared__ float red[16];
    if (lane == 0) red[wave] = acc;
    __syncthreads();
    if (tid == 0) {
        float t = 0.f;
#pragma unroll
        for (int i = 0; i < 16; i++) t += red[i];
        out[0] = t / (float)bn;
    }
}

extern "C" void kernel_launch(void* const* d_in, const int* in_sizes, int n_in,
                              void* d_out, int out_size, void* d_ws, size_t ws_size,
                              hipStream_t stream) {
    const float* x   = (const float*)d_in[0];
    const float* pos = (const float*)d_in[1];
    const float* neg = (const float*)d_in[2];
    const int bn = in_sizes[0] / DIM;  // 4096
    const int cn = in_sizes[2] / DIM;  // 8192

    // ws layout: Xn fp8 [bn*DIM] | Nn fp8 [cn*DIM] | sim f32 [bn] | rowsum f32 [bn]
    unsigned char* Xn = (unsigned char*)d_ws;
    unsigned char* Nn = Xn + (size_t)bn * DIM;
    float* sim    = (float*)(Nn + (size_t)cn * DIM);
    float* rowsum = sim + bn;

    // opt in to 128 KB dynamic LDS. Host-side attribute set — graph-safe.
    static bool attr_done = false;
    if (!attr_done) {
        (void)hipFuncSetAttribute((const void*)gemm_exp_rowsum,
                                  hipFuncAttributeMaxDynamicSharedMemorySize,
                                  131072);
        attr_done = true;
    }

    prep_all<<<dim3((bn + cn) / 4), dim3(256), 0, stream>>>(x, pos, neg, Xn, Nn, sim, rowsum, bn);
    gemm_exp_rowsum<<<dim3(cn / 256, bn / 256), dim3(512), 131072, stream>>>(Xn, Nn, rowsum);
    loss_kernel<<<dim3(1), dim3(1024), 0, stream>>>(rowsum, sim, (float*)d_out, bn);
}

// Round 7
// 188.226 us; speedup vs baseline: 1.3415x; 1.3415x over previous
//
#include <hip/hip_runtime.h>
#include <stdint.h>
#include <stddef.h>

#define DIM 1024
#define EPS 1e-8f

typedef __attribute__((ext_vector_type(4)))  int   i32x4;
typedef __attribute__((ext_vector_type(8)))  int   i32x8;
typedef __attribute__((ext_vector_type(4)))  float f32x4;

// e8m0 scale byte 123 = 2^(123-127) = 1/16 per operand -> 1/256 on the product,
// exactly cancelling the x16 prep scaling (bit-exact pow2 exponent shift).
#define SCALE8 0x7B7B7B7B

// async global->LDS, 16B per lane, wave-uniform LDS base + lane*16
__device__ __forceinline__ void async_copy16(const void* g, void* l) {
    __builtin_amdgcn_global_load_lds(
        (__attribute__((address_space(1))) void*)const_cast<void*>(g),
        (__attribute__((address_space(3))) void*)(l), 16, 0, 0);
}

// ---------------------------------------------------------------------------
// Prep: wave-per-row. Unit-normalize, scale by 16 (undone by hw e8m0 scales in
// the GEMM), cast to OCP fp8 e4m3, store rows LINEARLY with coalesced dword
// stores. The GEMM's staging-side chunk XOR supplies the LDS bank swizzle.
// ---------------------------------------------------------------------------
__global__ __launch_bounds__(256)
void prep_all(const float* __restrict__ x, const float* __restrict__ pos,
              const float* __restrict__ neg,
              unsigned char* __restrict__ Xn, unsigned char* __restrict__ Nn,
              float* __restrict__ simOut, float* __restrict__ rowsum, int bn) {
    const int lane = threadIdx.x & 63;
    const int wave = threadIdx.x >> 6;
    const int grow = blockIdx.x * 4 + wave;
    const bool isX = grow < bn;
    const int row  = isX ? grow : grow - bn;
    const float* src = isX ? x : neg;
    unsigned char* dst = isX ? Xn : Nn;

    const float4* s = (const float4*)(src + (size_t)row * DIM);
    float4 xv[4], pv[4];
    float sxx = 0.f, spp = 0.f, sxp = 0.f;
#pragma unroll
    for (int i = 0; i < 4; i++) {
        xv[i] = s[lane + 64 * i];
        sxx += xv[i].x * xv[i].x + xv[i].y * xv[i].y + xv[i].z * xv[i].z + xv[i].w * xv[i].w;
    }
    if (isX) {
        const float4* p = (const float4*)(pos + (size_t)row * DIM);
#pragma unroll
        for (int i = 0; i < 4; i++) {
            pv[i] = p[lane + 64 * i];
            spp += pv[i].x * pv[i].x + pv[i].y * pv[i].y + pv[i].z * pv[i].z + pv[i].w * pv[i].w;
            sxp += xv[i].x * pv[i].x + xv[i].y * pv[i].y + xv[i].z * pv[i].z + xv[i].w * pv[i].w;
        }
#pragma unroll
        for (int off = 1; off < 64; off <<= 1) {
            sxx += __shfl_xor(sxx, off);
            spp += __shfl_xor(spp, off);
            sxp += __shfl_xor(sxp, off);
        }
    } else {
#pragma unroll
        for (int off = 1; off < 64; off <<= 1) sxx += __shfl_xor(sxx, off);
    }
    const float nx  = sqrtf(sxx);
    const float inv = (nx > 0.f) ? (16.f / nx) : 0.f;   // x16 -> e4m3 sweet spot
    if (isX && lane == 0) {
        const float np = sqrtf(spp);
        simOut[row] = sxp / fmaxf(nx * np, EPS);
        rowsum[row] = 0.f;
    }
    unsigned int t;
    t = __builtin_amdgcn_cvt_pk_fp8_f32(xv[0].x * inv, xv[0].y * inv, 0, false);
    unsigned int q0 = __builtin_amdgcn_cvt_pk_fp8_f32(xv[0].z * inv, xv[0].w * inv, t, true);
    t = __builtin_amdgcn_cvt_pk_fp8_f32(xv[1].x * inv, xv[1].y * inv, 0, false);
    unsigned int q1 = __builtin_amdgcn_cvt_pk_fp8_f32(xv[1].z * inv, xv[1].w * inv, t, true);
    t = __builtin_amdgcn_cvt_pk_fp8_f32(xv[2].x * inv, xv[2].y * inv, 0, false);
    unsigned int q2 = __builtin_amdgcn_cvt_pk_fp8_f32(xv[2].z * inv, xv[2].w * inv, t, true);
    t = __builtin_amdgcn_cvt_pk_fp8_f32(xv[3].x * inv, xv[3].y * inv, 0, false);
    unsigned int q3 = __builtin_amdgcn_cvt_pk_fp8_f32(xv[3].z * inv, xv[3].w * inv, t, true);

    unsigned int* wr = (unsigned int*)(dst + (size_t)row * DIM);
    wr[lane]       = q0;
    wr[lane + 64]  = q1;
    wr[lane + 128] = q2;
    wr[lane + 192] = q3;
}

// ---------------------------------------------------------------------------
// Fused MX-fp8 GEMM: rowsum[i] += sum_j exp( unit(x_i) . unit(neg_j) )
// Cell: mfma_scale_f32_16x16x128_f8f6f4 (proven). 128x128 tile, 4 waves
// (2m x 2n), per-wave 64x64 = 4x4 frags, acc = 64 regs (R6 lesson: >64 acc
// regs spills — WRITE_SIZE 351 MB — never again).
// HYBRID OPERAND PATH (this round's change): B staged in LDS with the
// verified swizzle + R4's exact counted-vmcnt ledger; A read DIRECTLY from
// global into fragments (2x global_load_dwordx4 per frag; the 16x128 frag =
// 16 rows x 32 contiguous bytes -> every fetched byte consumed; Xn/Nn are
// L1/L2-resident). This halves LDS-port demand per block-window
// (~576 cy vs R4's ~1910) to match MFMA demand (552 cy) — R4 closed at
// 93% LDS-port saturation, which was the cap.
// Ledger (unchanged from R4, 4 glds/wave/window, vmcnt in-order retire —
// interleaved A-loads are OLDER than the newest 4 glds, so vmcnt(4) still
// proves window w+1 landed): prologue stages 0,1 then wait(4); window w<=5
// stages w+2 into buf (w+2)%3, boundary wait(4); w==6 wait(0); w==7 none.
// 3 x 16 KB static LDS, 3 blocks/CU (R3's proven desync regime).
// B LDS swizzle (verified): slot p of row r holds logical chunk p ^ (r&7);
// staging sch=(lane&7)^(lane>>3); read c0=((2q)^(mrow&7))<<4, pair at ^16.
// ---------------------------------------------------------------------------
__global__ __launch_bounds__(256, 3)
void gemm_exp_rowsum(const unsigned char* __restrict__ Xn,
                     const unsigned char* __restrict__ Nn,
                     float* __restrict__ rowsum) {
    constexpr int KB = DIM;          // 1024 bytes per fp8 row
    constexpr int BK = 128;          // bytes per k-window (K=128 elems)
    __shared__ __align__(16) unsigned char Bsh[3][128 * BK];   // 3 x 16 KB

    const int tid  = threadIdx.x;
    const int lane = tid & 63;
    const int wave = tid >> 6;                 // 0..3

    // T1: bijective chunked XCD swizzle (nwg = 2048, divisible by 8)
    const int nwg  = gridDim.x * gridDim.y;
    const int bid  = blockIdx.y * gridDim.x + blockIdx.x;
    const int swz  = (bid & 7) * (nwg >> 3) + (bid >> 3);
    const int rowBase = (swz / gridDim.x) * 128;
    const int colBase = (swz % gridDim.x) * 128;

    // B staging: one glds = 1 KB = 8 rows x 128 B; wave stages rows
    // [wave*32, +32): 4 glds per window.
    const int srow = lane >> 3;                 // 0..7
    const int sch  = (lane & 7) ^ srow;         // global-side swizzle
    const unsigned char* gB = Nn + (size_t)(colBase + wave * 32 + srow) * KB + sch * 16;

    const f32x4 fz = {0.f, 0.f, 0.f, 0.f};
    f32x4 acc[4][4];
#pragma unroll
    for (int mi = 0; mi < 4; mi++)
#pragma unroll
        for (int ni = 0; ni < 4; ni++) acc[mi][ni] = fz;

    const int m0   = (wave >> 1) * 64;
    const int n0   = (wave & 1) * 64;
    const int mrow = lane & 15;          // fragment row
    const int q    = lane >> 4;          // k-quarter: bytes [32q, 32q+32)
    const int c0   = ((2 * q) ^ (mrow & 7)) << 4;   // B slot; 2nd b128 at ^16

    // A direct-from-global fragment base: row rowBase+m0+mrow, k-offset 32q.
    const unsigned char* gAbase =
        Xn + (size_t)(rowBase + m0 + mrow) * KB + 32 * q;

    int boff[4];
#pragma unroll
    for (int i = 0; i < 4; i++) boff[i] = (n0 + 16 * i + mrow) * BK + c0;

#define STAGE(buf, stg)                                                        \
    do {                                                                       \
        const int kq = (stg) * BK;                                             \
        _Pragma("unroll")                                                      \
        for (int i = 0; i < 4; i++)                                            \
            async_copy16(gB + (size_t)(8 * i) * KB + kq,                       \
                         &Bsh[buf][(wave * 32 + 8 * i) * BK]);                 \
    } while (0)

    // prologue: windows 0,1 in flight (8 glds); retire window 0, keep 4.
    STAGE(0, 0);
    STAGE(1, 1);
    asm volatile("s_waitcnt vmcnt(4)\n\ts_barrier" ::: "memory");

#pragma unroll
    for (int w = 0; w < 8; w++) {
        const unsigned char* Bb = Bsh[w % 3];
        if (w <= 5) STAGE((w + 2) % 3, w + 2);
        // A fragments direct from global (L1/L2-resident): issue all 8 loads
        // early so latency hides under the B ds_reads + MFMA ramp.
        const unsigned char* gAw = gAbase + w * BK;
        i32x8 Af[4], Bf[4];
#pragma unroll
        for (int mi = 0; mi < 4; mi++) {
            i32x4 lo = *(const i32x4*)(gAw + (size_t)(16 * mi) * KB);
            i32x4 hi = *(const i32x4*)(gAw + (size_t)(16 * mi) * KB + 16);
            Af[mi] = __builtin_shufflevector(lo, hi, 0, 1, 2, 3, 4, 5, 6, 7);
        }
#pragma unroll
        for (int i = 0; i < 4; i++) {
            i32x4 lo = *(const i32x4*)(Bb + boff[i]);
            i32x4 hi = *(const i32x4*)(Bb + (boff[i] ^ 16));
            Bf[i] = __builtin_shufflevector(lo, hi, 0, 1, 2, 3, 4, 5, 6, 7);
        }
        __builtin_amdgcn_s_setprio(1);
#pragma unroll
        for (int mi = 0; mi < 4; mi++)
#pragma unroll
            for (int ni = 0; ni < 4; ni++)
                acc[mi][ni] = __builtin_amdgcn_mfma_scale_f32_16x16x128_f8f6f4(
                    Af[mi], Bf[ni], acc[mi][ni], 0, 0, 0, SCALE8, 0, SCALE8);
        __builtin_amdgcn_s_setprio(0);
        // window boundary: counted wait (in-order vmcnt retire => all glds
        // older than the newest 4 have landed), never 0 until the tail.
        if (w <= 5) {
            asm volatile("s_waitcnt vmcnt(4)\n\ts_barrier" ::: "memory");
        } else if (w == 6) {
            asm volatile("s_waitcnt vmcnt(0)\n\ts_barrier" ::: "memory");
        }
    }
#undef STAGE

    // epilogue (verified): 16x16 C/D layout col=lane&15, row=q*4+reg.
    // exp, sum 4 ni blocks, 16-col shuffle reduce, 4 atomics per q-lane.
#pragma unroll
    for (int mi = 0; mi < 4; mi++) {
        float rs0 = 0.f, rs1 = 0.f, rs2 = 0.f, rs3 = 0.f;
#pragma unroll
        for (int ni = 0; ni < 4; ni++) {
            rs0 += __expf(acc[mi][ni].x);
            rs1 += __expf(acc[mi][ni].y);
            rs2 += __expf(acc[mi][ni].z);
            rs3 += __expf(acc[mi][ni].w);
        }
#pragma unroll
        for (int off = 1; off < 16; off <<= 1) {
            rs0 += __shfl_xor(rs0, off);
            rs1 += __shfl_xor(rs1, off);
            rs2 += __shfl_xor(rs2, off);
            rs3 += __shfl_xor(rs3, off);
        }
        if ((lane & 15) == 0) {
            const int r = rowBase + m0 + mi * 16 + q * 4;
            atomicAdd(&rowsum[r + 0], rs0);
            atomicAdd(&rowsum[r + 1], rs1);
            atomicAdd(&rowsum[r + 2], rs2);
            atomicAdd(&rowsum[r + 3], rs3);
        }
    }
}

__global__ __launch_bounds__(1024)
void loss_kernel(const float* __restrict__ rowsum, const float* __restrict__ sim,
                 float* __restrict__ out, int bn) {
    const int tid  = threadIdx.x;
    const int lane = tid & 63;
    const int wave = tid >> 6;
    float acc = 0.f;
    for (int i = tid; i < bn; i += 1024) acc += logf(rowsum[i]) - sim[i];
#pragma unroll
    for (int off = 1; off < 64; off <<= 1) acc += __shfl_xor(acc, off);
    __shared__ float red[16];
    if (lane == 0) red[wave] = acc;
    __syncthreads();
    if (tid == 0) {
        float t = 0.f;
#pragma unroll
        for (int i = 0; i < 16; i++) t += red[i];
        out[0] = t / (float)bn;
    }
}

extern "C" void kernel_launch(void* const* d_in, const int* in_sizes, int n_in,
                              void* d_out, int out_size, void* d_ws, size_t ws_size,
                              hipStream_t stream) {
    const float* x   = (const float*)d_in[0];
    const float* pos = (const float*)d_in[1];
    const float* neg = (const float*)d_in[2];
    const int bn = in_sizes[0] / DIM;  // 4096
    const int cn = in_sizes[2] / DIM;  // 8192

    // ws layout: Xn fp8 [bn*DIM] | Nn fp8 [cn*DIM] | sim f32 [bn] | rowsum f32 [bn]
    unsigned char* Xn = (unsigned char*)d_ws;
    unsigned char* Nn = Xn + (size_t)bn * DIM;
    float* sim    = (float*)(Nn + (size_t)cn * DIM);
    float* rowsum = sim + bn;

    prep_all<<<dim3((bn + cn) / 4), dim3(256), 0, stream>>>(x, pos, neg, Xn, Nn, sim, rowsum, bn);
    gemm_exp_rowsum<<<dim3(cn / 128, bn / 128), dim3(256), 0, stream>>>(Xn, Nn, rowsum);
    loss_kernel<<<dim3(1), dim3(1024), 0, stream>>>(rowsum, sim, (float*)d_out, bn);
}

// Round 8
// 184.317 us; speedup vs baseline: 1.3699x; 1.0212x over previous
//
#include <hip/hip_runtime.h>
#include <stdint.h>
#include <stddef.h>

#define DIM 1024
#define EPS 1e-8f

typedef __attribute__((ext_vector_type(4)))  int   i32x4;
typedef __attribute__((ext_vector_type(8)))  int   i32x8;
typedef __attribute__((ext_vector_type(4)))  float f32x4;

// e8m0 scale byte 123 = 2^(123-127) = 1/16 per operand -> 1/256 on the product,
// exactly cancelling the x16 prep scaling (bit-exact pow2 exponent shift).
#define SCALE8 0x7B7B7B7B

// async global->LDS, 16B per lane, wave-uniform LDS base + lane*16
__device__ __forceinline__ void async_copy16(const void* g, void* l) {
    __builtin_amdgcn_global_load_lds(
        (__attribute__((address_space(1))) void*)const_cast<void*>(g),
        (__attribute__((address_space(3))) void*)(l), 16, 0, 0);
}

// ---------------------------------------------------------------------------
// Prep: wave-per-row. Unit-normalize, scale by 16 (undone by hw e8m0 scales in
// the GEMM), cast to OCP fp8 e4m3, store rows LINEARLY with coalesced dword
// stores. The GEMM's staging-side chunk XOR supplies the LDS bank swizzle.
// ---------------------------------------------------------------------------
__global__ __launch_bounds__(256)
void prep_all(const float* __restrict__ x, const float* __restrict__ pos,
              const float* __restrict__ neg,
              unsigned char* __restrict__ Xn, unsigned char* __restrict__ Nn,
              float* __restrict__ simOut, float* __restrict__ rowsum, int bn) {
    const int lane = threadIdx.x & 63;
    const int wave = threadIdx.x >> 6;
    const int grow = blockIdx.x * 4 + wave;
    const bool isX = grow < bn;
    const int row  = isX ? grow : grow - bn;
    const float* src = isX ? x : neg;
    unsigned char* dst = isX ? Xn : Nn;

    const float4* s = (const float4*)(src + (size_t)row * DIM);
    float4 xv[4], pv[4];
    float sxx = 0.f, spp = 0.f, sxp = 0.f;
#pragma unroll
    for (int i = 0; i < 4; i++) {
        xv[i] = s[lane + 64 * i];
        sxx += xv[i].x * xv[i].x + xv[i].y * xv[i].y + xv[i].z * xv[i].z + xv[i].w * xv[i].w;
    }
    if (isX) {
        const float4* p = (const float4*)(pos + (size_t)row * DIM);
#pragma unroll
        for (int i = 0; i < 4; i++) {
            pv[i] = p[lane + 64 * i];
            spp += pv[i].x * pv[i].x + pv[i].y * pv[i].y + pv[i].z * pv[i].z + pv[i].w * pv[i].w;
            sxp += xv[i].x * pv[i].x + xv[i].y * pv[i].y + xv[i].z * pv[i].z + xv[i].w * pv[i].w;
        }
#pragma unroll
        for (int off = 1; off < 64; off <<= 1) {
            sxx += __shfl_xor(sxx, off);
            spp += __shfl_xor(spp, off);
            sxp += __shfl_xor(sxp, off);
        }
    } else {
#pragma unroll
        for (int off = 1; off < 64; off <<= 1) sxx += __shfl_xor(sxx, off);
    }
    const float nx  = sqrtf(sxx);
    const float inv = (nx > 0.f) ? (16.f / nx) : 0.f;   // x16 -> e4m3 sweet spot
    if (isX && lane == 0) {
        const float np = sqrtf(spp);
        simOut[row] = sxp / fmaxf(nx * np, EPS);
        rowsum[row] = 0.f;
    }
    unsigned int t;
    t = __builtin_amdgcn_cvt_pk_fp8_f32(xv[0].x * inv, xv[0].y * inv, 0, false);
    unsigned int q0 = __builtin_amdgcn_cvt_pk_fp8_f32(xv[0].z * inv, xv[0].w * inv, t, true);
    t = __builtin_amdgcn_cvt_pk_fp8_f32(xv[1].x * inv, xv[1].y * inv, 0, false);
    unsigned int q1 = __builtin_amdgcn_cvt_pk_fp8_f32(xv[1].z * inv, xv[1].w * inv, t, true);
    t = __builtin_amdgcn_cvt_pk_fp8_f32(xv[2].x * inv, xv[2].y * inv, 0, false);
    unsigned int q2 = __builtin_amdgcn_cvt_pk_fp8_f32(xv[2].z * inv, xv[2].w * inv, t, true);
    t = __builtin_amdgcn_cvt_pk_fp8_f32(xv[3].x * inv, xv[3].y * inv, 0, false);
    unsigned int q3 = __builtin_amdgcn_cvt_pk_fp8_f32(xv[3].z * inv, xv[3].w * inv, t, true);

    unsigned int* wr = (unsigned int*)(dst + (size_t)row * DIM);
    wr[lane]       = q0;
    wr[lane + 64]  = q1;
    wr[lane + 128] = q2;
    wr[lane + 192] = q3;
}

// ---------------------------------------------------------------------------
// Fused MX-fp8 GEMM: rowsum[i] += sum_j exp( unit(x_i) . unit(neg_j) )
// Cell: mfma_scale_f32_16x16x128_f8f6f4 (proven). 128x128 tile, 4 waves
// (2m x 2n), per-wave 64x64 = 4x4 frags, acc = 64 regs (R6 spill cap).
// BOTH operands through LDS with coalesced glds (R7 lesson: per-lane
// direct-from-global fragments stride 1KB -> 4x transaction amplification,
// FETCH 138 MB; never again).
// Schedule (this round's change): TWO-buffer, single barrier per window,
// T14 issue-early/drain-late, TWO blocks/CU for desync:
//   prologue: STAGE(0,0); vmcnt(0); barrier
//   window w: STAGE(w+1 -> buf^1) at top; 16 ds_read_b128; setprio 16 MFMA;
//             vmcnt(0)+barrier  (waits on loads issued a full read+MFMA
//             phase earlier -> ~zero exposed latency; R3's stall was
//             issue->wait with nothing between).
// Overwrite hazard: STAGE(w+1) writes buf (w+1)&1, whose window-(w-1)
// readers all passed the (w-1)->w boundary barrier. Single-barrier-safe.
// R4 ledger autopsy: at 1 block/CU its window wall was 4950 cy vs
// MFMA 1104 + LDS 1920 -> ~3000 cy lockstep sync skew. 64 KB LDS here
// gives 2 blocks/CU; desynced blocks fill each other's barrier gaps
// (m114 mechanism, proven in R0/R3 this session).
// LDS swizzle (verified): slot p of row r holds logical chunk p ^ (r&7);
// staging sch=(lane&7)^(lane>>3), glds dest linear. Read: mrow=lane&15,
// q=lane>>4 owns k-bytes [32q,32q+32) via b128 at slot (2q)^(mrow&7), ^16.
// ---------------------------------------------------------------------------
__global__ __launch_bounds__(256, 2)
void gemm_exp_rowsum(const unsigned char* __restrict__ Xn,
                     const unsigned char* __restrict__ Nn,
                     float* __restrict__ rowsum) {
    constexpr int KB = DIM;          // 1024 bytes per fp8 row
    constexpr int BK = 128;          // bytes per k-window (K=128 elems)
    __shared__ __align__(16) unsigned char Ash[2][128 * BK];   // 2 x 16 KB
    __shared__ __align__(16) unsigned char Bsh[2][128 * BK];   // 2 x 16 KB

    const int tid  = threadIdx.x;
    const int lane = tid & 63;
    const int wave = tid >> 6;                 // 0..3

    // T1: bijective chunked XCD swizzle (nwg = 2048, divisible by 8)
    const int nwg  = gridDim.x * gridDim.y;
    const int bid  = blockIdx.y * gridDim.x + blockIdx.x;
    const int swz  = (bid & 7) * (nwg >> 3) + (bid >> 3);
    const int rowBase = (swz / gridDim.x) * 128;
    const int colBase = (swz % gridDim.x) * 128;

    // staging: one glds = 1 KB = 8 rows x 128 B; wave stages A rows
    // [wave*32,+32) and B rows [wave*32,+32): 4+4 glds per window.
    const int srow = lane >> 3;                 // 0..7
    const int sch  = (lane & 7) ^ srow;         // global-side swizzle
    const unsigned char* gA = Xn + (size_t)(rowBase + wave * 32 + srow) * KB + sch * 16;
    const unsigned char* gB = Nn + (size_t)(colBase + wave * 32 + srow) * KB + sch * 16;

    const f32x4 fz = {0.f, 0.f, 0.f, 0.f};
    f32x4 acc[4][4];
#pragma unroll
    for (int mi = 0; mi < 4; mi++)
#pragma unroll
        for (int ni = 0; ni < 4; ni++) acc[mi][ni] = fz;

    const int m0   = (wave >> 1) * 64;
    const int n0   = (wave & 1) * 64;
    const int mrow = lane & 15;          // fragment row
    const int q    = lane >> 4;          // k-quarter: bytes [32q, 32q+32)
    const int c0   = ((2 * q) ^ (mrow & 7)) << 4;   // slot; 2nd b128 at ^16

    int aoff[4], boff[4];
#pragma unroll
    for (int i = 0; i < 4; i++) {
        aoff[i] = (m0 + 16 * i + mrow) * BK + c0;
        boff[i] = (n0 + 16 * i + mrow) * BK + c0;
    }

#define STAGE(buf, stg)                                                        \
    do {                                                                       \
        const int kq = (stg) * BK;                                             \
        _Pragma("unroll")                                                      \
        for (int i = 0; i < 4; i++) {                                          \
            async_copy16(gA + (size_t)(8 * i) * KB + kq,                       \
                         &Ash[buf][(wave * 32 + 8 * i) * BK]);                 \
            async_copy16(gB + (size_t)(8 * i) * KB + kq,                       \
                         &Bsh[buf][(wave * 32 + 8 * i) * BK]);                 \
        }                                                                      \
    } while (0)

    // prologue: window 0 staged and drained (nothing to overlap yet).
    STAGE(0, 0);
    asm volatile("s_waitcnt vmcnt(0)\n\ts_barrier" ::: "memory");

#pragma unroll
    for (int w = 0; w < 8; w++) {
        const int b = w & 1;
        if (w < 7) STAGE(b ^ 1, w + 1);   // issue early: hides under compute
        i32x8 Af[4], Bf[4];
#pragma unroll
        for (int i = 0; i < 4; i++) {
            i32x4 alo = *(const i32x4*)(&Ash[b][aoff[i]]);
            i32x4 ahi = *(const i32x4*)(&Ash[b][aoff[i] ^ 16]);
            Af[i] = __builtin_shufflevector(alo, ahi, 0, 1, 2, 3, 4, 5, 6, 7);
            i32x4 blo = *(const i32x4*)(&Bsh[b][boff[i]]);
            i32x4 bhi = *(const i32x4*)(&Bsh[b][boff[i] ^ 16]);
            Bf[i] = __builtin_shufflevector(blo, bhi, 0, 1, 2, 3, 4, 5, 6, 7);
        }
        __builtin_amdgcn_s_setprio(1);
#pragma unroll
        for (int mi = 0; mi < 4; mi++)
#pragma unroll
            for (int ni = 0; ni < 4; ni++)
                acc[mi][ni] = __builtin_amdgcn_mfma_scale_f32_16x16x128_f8f6f4(
                    Af[mi], Bf[ni], acc[mi][ni], 0, 0, 0, SCALE8, 0, SCALE8);
        __builtin_amdgcn_s_setprio(0);
        // boundary: drain the loads issued at THIS window's top (a full
        // read+MFMA phase ago -> ~zero exposed latency), then barrier.
        if (w < 7)
            asm volatile("s_waitcnt vmcnt(0)\n\ts_barrier" ::: "memory");
    }
#undef STAGE

    // epilogue (verified): 16x16 C/D layout col=lane&15, row=q*4+reg.
    // exp, sum 4 ni blocks, 16-col shuffle reduce, 4 atomics per q-lane.
#pragma unroll
    for (int mi = 0; mi < 4; mi++) {
        float rs0 = 0.f, rs1 = 0.f, rs2 = 0.f, rs3 = 0.f;
#pragma unroll
        for (int ni = 0; ni < 4; ni++) {
            rs0 += __expf(acc[mi][ni].x);
            rs1 += __expf(acc[mi][ni].y);
            rs2 += __expf(acc[mi][ni].z);
            rs3 += __expf(acc[mi][ni].w);
        }
#pragma unroll
        for (int off = 1; off < 16; off <<= 1) {
            rs0 += __shfl_xor(rs0, off);
            rs1 += __shfl_xor(rs1, off);
            rs2 += __shfl_xor(rs2, off);
            rs3 += __shfl_xor(rs3, off);
        }
        if ((lane & 15) == 0) {
            const int r = rowBase + m0 + mi * 16 + q * 4;
            atomicAdd(&rowsum[r + 0], rs0);
            atomicAdd(&rowsum[r + 1], rs1);
            atomicAdd(&rowsum[r + 2], rs2);
            atomicAdd(&rowsum[r + 3], rs3);
        }
    }
}

__global__ __launch_bounds__(1024)
void loss_kernel(const float* __restrict__ rowsum, const float* __restrict__ sim,
                 float* __restrict__ out, int bn) {
    const int tid  = threadIdx.x;
    const int lane = tid & 63;
    const int wave = tid >> 6;
    float acc = 0.f;
    for (int i = tid; i < bn; i += 1024) acc += logf(rowsum[i]) - sim[i];
#pragma unroll
    for (int off = 1; off < 64; off <<= 1) acc += __shfl_xor(acc, off);
    __shared__ float red[16];
    if (lane == 0) red[wave] = acc;
    __syncthreads();
    if (tid == 0) {
        float t = 0.f;
#pragma unroll
        for (int i = 0; i < 16; i++) t += red[i];
        out[0] = t / (float)bn;
    }
}

extern "C" void kernel_launch(void* const* d_in, const int* in_sizes, int n_in,
                              void* d_out, int out_size, void* d_ws, size_t ws_size,
                              hipStream_t stream) {
    const float* x   = (const float*)d_in[0];
    const float* pos = (const float*)d_in[1];
    const float* neg = (const float*)d_in[2];
    const int bn = in_sizes[0] / DIM;  // 4096
    const int cn = in_sizes[2] / DIM;  // 8192

    // ws layout: Xn fp8 [bn*DIM] | Nn fp8 [cn*DIM] | sim f32 [bn] | rowsum f32 [bn]
    unsigned char* Xn = (unsigned char*)d_ws;
    unsigned char* Nn = Xn + (size_t)bn * DIM;
    float* sim    = (float*)(Nn + (size_t)cn * DIM);
    float* rowsum = sim + bn;

    prep_all<<<dim3((bn + cn) / 4), dim3(256), 0, stream>>>(x, pos, neg, Xn, Nn, sim, rowsum, bn);
    gemm_exp_rowsum<<<dim3(cn / 128, bn / 128), dim3(256), 0, stream>>>(Xn, Nn, rowsum);
    loss_kernel<<<dim3(1), dim3(1024), 0, stream>>>(rowsum, sim, (float*)d_out, bn);
}

// Round 9
// 171.846 us; speedup vs baseline: 1.4694x; 1.0726x over previous
//
#include <hip/hip_runtime.h>
#include <stdint.h>
#include <stddef.h>

#define DIM 1024
#define EPS 1e-8f

typedef __attribute__((ext_vector_type(4)))  int   i32x4;
typedef __attribute__((ext_vector_type(8)))  int   i32x8;
typedef __attribute__((ext_vector_type(4)))  float f32x4;

// e8m0 scale byte 123 = 2^(123-127) = 1/16 per operand -> 1/256 on the product,
// exactly cancelling the x16 prep scaling (bit-exact pow2 exponent shift).
#define SCALE8 0x7B7B7B7B

// async global->LDS, 16B per lane, wave-uniform LDS base + lane*16
__device__ __forceinline__ void async_copy16(const void* g, void* l) {
    __builtin_amdgcn_global_load_lds(
        (__attribute__((address_space(1))) void*)const_cast<void*>(g),
        (__attribute__((address_space(3))) void*)(l), 16, 0, 0);
}

// ---------------------------------------------------------------------------
// Prep: wave-per-row. Unit-normalize, scale by 16 (undone by hw e8m0 scales in
// the GEMM), cast to OCP fp8 e4m3, store rows LINEARLY with coalesced dword
// stores. The GEMM's staging-side chunk XOR supplies the LDS bank swizzle.
// ---------------------------------------------------------------------------
__global__ __launch_bounds__(256)
void prep_all(const float* __restrict__ x, const float* __restrict__ pos,
              const float* __restrict__ neg,
              unsigned char* __restrict__ Xn, unsigned char* __restrict__ Nn,
              float* __restrict__ simOut, float* __restrict__ rowsum, int bn) {
    const int lane = threadIdx.x & 63;
    const int wave = threadIdx.x >> 6;
    const int grow = blockIdx.x * 4 + wave;
    const bool isX = grow < bn;
    const int row  = isX ? grow : grow - bn;
    const float* src = isX ? x : neg;
    unsigned char* dst = isX ? Xn : Nn;

    const float4* s = (const float4*)(src + (size_t)row * DIM);
    float4 xv[4], pv[4];
    float sxx = 0.f, spp = 0.f, sxp = 0.f;
#pragma unroll
    for (int i = 0; i < 4; i++) {
        xv[i] = s[lane + 64 * i];
        sxx += xv[i].x * xv[i].x + xv[i].y * xv[i].y + xv[i].z * xv[i].z + xv[i].w * xv[i].w;
    }
    if (isX) {
        const float4* p = (const float4*)(pos + (size_t)row * DIM);
#pragma unroll
        for (int i = 0; i < 4; i++) {
            pv[i] = p[lane + 64 * i];
            spp += pv[i].x * pv[i].x + pv[i].y * pv[i].y + pv[i].z * pv[i].z + pv[i].w * pv[i].w;
            sxp += xv[i].x * pv[i].x + xv[i].y * pv[i].y + xv[i].z * pv[i].z + xv[i].w * pv[i].w;
        }
#pragma unroll
        for (int off = 1; off < 64; off <<= 1) {
            sxx += __shfl_xor(sxx, off);
            spp += __shfl_xor(spp, off);
            sxp += __shfl_xor(sxp, off);
        }
    } else {
#pragma unroll
        for (int off = 1; off < 64; off <<= 1) sxx += __shfl_xor(sxx, off);
    }
    const float nx  = sqrtf(sxx);
    const float inv = (nx > 0.f) ? (16.f / nx) : 0.f;   // x16 -> e4m3 sweet spot
    if (isX && lane == 0) {
        const float np = sqrtf(spp);
        simOut[row] = sxp / fmaxf(nx * np, EPS);
        rowsum[row] = 0.f;
    }
    unsigned int t;
    t = __builtin_amdgcn_cvt_pk_fp8_f32(xv[0].x * inv, xv[0].y * inv, 0, false);
    unsigned int q0 = __builtin_amdgcn_cvt_pk_fp8_f32(xv[0].z * inv, xv[0].w * inv, t, true);
    t = __builtin_amdgcn_cvt_pk_fp8_f32(xv[1].x * inv, xv[1].y * inv, 0, false);
    unsigned int q1 = __builtin_amdgcn_cvt_pk_fp8_f32(xv[1].z * inv, xv[1].w * inv, t, true);
    t = __builtin_amdgcn_cvt_pk_fp8_f32(xv[2].x * inv, xv[2].y * inv, 0, false);
    unsigned int q2 = __builtin_amdgcn_cvt_pk_fp8_f32(xv[2].z * inv, xv[2].w * inv, t, true);
    t = __builtin_amdgcn_cvt_pk_fp8_f32(xv[3].x * inv, xv[3].y * inv, 0, false);
    unsigned int q3 = __builtin_amdgcn_cvt_pk_fp8_f32(xv[3].z * inv, xv[3].w * inv, t, true);

    unsigned int* wr = (unsigned int*)(dst + (size_t)row * DIM);
    wr[lane]       = q0;
    wr[lane + 64]  = q1;
    wr[lane + 128] = q2;
    wr[lane + 192] = q3;
}

// ---------------------------------------------------------------------------
// Fused MX-fp8 GEMM: rowsum[i] += sum_j exp( unit(x_i) . unit(neg_j) )
// BASE = R4 (best known, 66 us): 256x128 tile, 8 waves, per-wave 64x64
// (4x4 frags of mfma_scale_f32_16x16x128_f8f6f4), BK=128-B windows,
// THREE-buffer rotation (144 KB dyn LDS), prefetch distance 2, counted
// s_waitcnt vmcnt(6) at window boundaries only (never 0 until the tail).
// Two bounded changes on top:
// (1) 4 QUADRANT PHASES per window (m196/m201 fine-interleave lever):
//     ph0 {stage 2 glds | RD A01,B01 (8 b128) | 4 MFMA mi01 x ni01}
//     ph1 {stage 2 glds | RD B23   (4 b128)   | 4 MFMA mi01 x ni23}
//     ph2 {stage 1 glds | RD A23   (4 b128)   | 4 MFMA mi23 x ni01}
//     ph3 {stage 1 glds |                     | 4 MFMA mi23 x ni23}
//     raw s_barrier between phases; boundary ledger unchanged from R4:
//     6 glds/wave/window for w+2; wait(6) => w+1 landed, w+2 in flight.
//     Smaller work quantum per barrier = less lockstep skew (R4 autopsy:
//     ~3000 of 4950 cy/window was skew, not port saturation).
// (2) 2-D REGION XCD MAPPING: each XCD owns an 8x16-block region ->
//     per-XCD set = A 2 MB + B 2 MB, BOTH fit the 4 MB L2 (R4's strip
//     mapping thrashed B; R8's doubled FETCH). Bijective on the 64x16 grid.
// LDS swizzle + fragment layout (verified): slot p of row r holds logical
// chunk p ^ (r&7); staging sch=(lane&7)^(lane>>3), glds dest linear.
// Read: mrow=lane&15, q=lane>>4 owns k-bytes [32q,32q+32) via b128 at
// slot (2q)^(mrow&7) and that ^16.
// ---------------------------------------------------------------------------
__global__ __launch_bounds__(512, 2)
void gemm_exp_rowsum(const unsigned char* __restrict__ Xn,
                     const unsigned char* __restrict__ Nn,
                     float* __restrict__ rowsum) {
    constexpr int KB   = DIM;            // 1024 bytes per fp8 row
    constexpr int BK   = 128;            // bytes per k-window (K=128 elems)
    constexpr int BOFF = 256 * BK;       // B area offset within a buffer (32 KB)
    constexpr int BUFB = BOFF + 128 * BK;  // 48 KB per buffer (A then B)
    extern __shared__ unsigned char smem[];  // 3 * BUFB = 144 KB

    const int tid  = threadIdx.x;
    const int lane = tid & 63;
    const int wave = tid >> 6;                 // 0..7

    // (2) 2-D region XCD mapping. Grid is fixed (64 cols x 16 rows of
    // blocks). xcd -> region (2 region-rows x 4 region-cols of 8x16 blocks);
    // within region: row-major (B panel reused across the 8 block-rows).
    const int bid  = blockIdx.y * gridDim.x + blockIdx.x;
    const int xcd  = bid & 7;
    const int idx  = bid >> 3;                 // 0..127
    const int brow = (xcd >> 2) * 8  + (idx >> 4);   // 0..15
    const int bcol = (xcd &  3) * 16 + (idx & 15);   // 0..63
    const int rowBase = brow * 256;
    const int colBase = bcol * 128;

    // staging: one glds = 1 KB = 8 rows x 128 B; wave stages A rows
    // [wave*32,+32) (4 glds) and B rows [wave*16,+16) (2 glds) per window.
    const int srow = lane >> 3;                 // 0..7
    const int sch  = (lane & 7) ^ srow;         // global-side swizzle
    const unsigned char* gA = Xn + (size_t)(rowBase + wave * 32 + srow) * KB + sch * 16;
    const unsigned char* gB = Nn + (size_t)(colBase + wave * 16 + srow) * KB + sch * 16;

    const f32x4 fz = {0.f, 0.f, 0.f, 0.f};
    f32x4 acc[4][4];
#pragma unroll
    for (int mi = 0; mi < 4; mi++)
#pragma unroll
        for (int ni = 0; ni < 4; ni++) acc[mi][ni] = fz;

    const int m0   = (wave >> 1) * 64;   // 0,64,128,192
    const int n0   = (wave & 1) * 64;    // 0,64
    const int mrow = lane & 15;
    const int q    = lane >> 4;          // k-quarter: bytes [32q, 32q+32)
    const int c0   = ((2 * q) ^ (mrow & 7)) << 4;

    int aoff[4], boff[4];
#pragma unroll
    for (int i = 0; i < 4; i++) {
        aoff[i] = (m0 + 16 * i + mrow) * BK + c0;
        boff[i] = BOFF + (n0 + 16 * i + mrow) * BK + c0;
    }

    // A-staging piece h (h=0..3): rows wave*32 + 8h .. +8   (1 glds)
#define STAGE_A(buf, stg, h)                                                   \
    async_copy16(gA + (size_t)(8 * (h)) * KB + (stg) * BK,                     \
                 smem + (buf) * BUFB + (wave * 32 + 8 * (h)) * BK)
    // B-staging piece h (h=0..1): rows wave*16 + 8h .. +8   (1 glds)
#define STAGE_B(buf, stg, h)                                                   \
    async_copy16(gB + (size_t)(8 * (h)) * KB + (stg) * BK,                     \
                 smem + (buf) * BUFB + BOFF + (wave * 16 + 8 * (h)) * BK)

#define RD(base, off, dst)                                                     \
    do {                                                                       \
        i32x4 lo_ = *(const i32x4*)((base) + (off));                           \
        i32x4 hi_ = *(const i32x4*)((base) + ((off) ^ 16));                    \
        dst = __builtin_shufflevector(lo_, hi_, 0, 1, 2, 3, 4, 5, 6, 7);       \
    } while (0)

#define MFMA4(MI0, NI0)                                                        \
    do {                                                                       \
        __builtin_amdgcn_s_setprio(1);                                         \
        _Pragma("unroll")                                                      \
        for (int mi_ = 0; mi_ < 2; mi_++)                                      \
            _Pragma("unroll")                                                  \
            for (int ni_ = 0; ni_ < 2; ni_++)                                  \
                acc[(MI0) + mi_][(NI0) + ni_] =                                \
                    __builtin_amdgcn_mfma_scale_f32_16x16x128_f8f6f4(          \
                        Af[(MI0) + mi_], Bf[(NI0) + ni_],                      \
                        acc[(MI0) + mi_][(NI0) + ni_], 0, 0, 0,                \
                        SCALE8, 0, SCALE8);                                    \
        __builtin_amdgcn_s_setprio(0);                                         \
    } while (0)

#define PH_BAR() asm volatile("s_barrier" ::: "memory")

    // prologue: windows 0,1 fully staged (12 glds); retire window 0, keep 6.
#pragma unroll
    for (int h = 0; h < 4; h++) { STAGE_A(0, 0, h); }
    STAGE_B(0, 0, 0); STAGE_B(0, 0, 1);
#pragma unroll
    for (int h = 0; h < 4; h++) { STAGE_A(1, 1, h); }
    STAGE_B(1, 1, 0); STAGE_B(1, 1, 1);
    asm volatile("s_waitcnt vmcnt(6)\n\ts_barrier" ::: "memory");

#pragma unroll
    for (int w = 0; w < 8; w++) {
        const int b  = w % 3;
        const int nb = (w + 2) % 3;
        const unsigned char* Lb = smem + b * BUFB;
        i32x8 Af[4], Bf[4];
        // ---- ph0: stage A0,A1 | read A01 + B01 | MFMA mi01 x ni01
        if (w < 6) { STAGE_A(nb, w + 2, 0); STAGE_A(nb, w + 2, 1); }
        RD(Lb, aoff[0], Af[0]); RD(Lb, aoff[1], Af[1]);
        RD(Lb, boff[0], Bf[0]); RD(Lb, boff[1], Bf[1]);
        MFMA4(0, 0);
        PH_BAR();
        // ---- ph1: stage A2,A3 | read B23 | MFMA mi01 x ni23
        if (w < 6) { STAGE_A(nb, w + 2, 2); STAGE_A(nb, w + 2, 3); }
        RD(Lb, boff[2], Bf[2]); RD(Lb, boff[3], Bf[3]);
        MFMA4(0, 2);
        PH_BAR();
        // ---- ph2: stage B0 | read A23 | MFMA mi23 x ni01
        if (w < 6) STAGE_B(nb, w + 2, 0);
        RD(Lb, aoff[2], Af[2]); RD(Lb, aoff[3], Af[3]);
        MFMA4(2, 0);
        PH_BAR();
        // ---- ph3: stage B1 | MFMA mi23 x ni23
        if (w < 6) STAGE_B(nb, w + 2, 1);
        MFMA4(2, 2);
        // ---- window boundary: counted wait (never 0 until the tail)
        if (w < 6) {
            asm volatile("s_waitcnt vmcnt(6)\n\ts_barrier" ::: "memory");
        } else if (w == 6) {
            asm volatile("s_waitcnt vmcnt(0)\n\ts_barrier" ::: "memory");
        }
    }
#undef STAGE_A
#undef STAGE_B
#undef RD
#undef MFMA4
#undef PH_BAR

    // epilogue (verified): 16x16 C/D layout col=lane&15, row=q*4+reg.
    // exp, sum 4 ni blocks, 16-col shuffle reduce, 4 atomics per q-lane.
#pragma unroll
    for (int mi = 0; mi < 4; mi++) {
        float rs0 = 0.f, rs1 = 0.f, rs2 = 0.f, rs3 = 0.f;
#pragma unroll
        for (int ni = 0; ni < 4; ni++) {
            rs0 += __expf(acc[mi][ni].x);
            rs1 += __expf(acc[mi][ni].y);
            rs2 += __expf(acc[mi][ni].z);
            rs3 += __expf(acc[mi][ni].w);
        }
#pragma unroll
        for (int off = 1; off < 16; off <<= 1) {
            rs0 += __shfl_xor(rs0, off);
            rs1 += __shfl_xor(rs1, off);
            rs2 += __shfl_xor(rs2, off);
            rs3 += __shfl_xor(rs3, off);
        }
        if ((lane & 15) == 0) {
            const int r = rowBase + m0 + mi * 16 + q * 4;
            atomicAdd(&rowsum[r + 0], rs0);
            atomicAdd(&rowsum[r + 1], rs1);
            atomicAdd(&rowsum[r + 2], rs2);
            atomicAdd(&rowsum[r + 3], rs3);
        }
    }
}

__global__ __launch_bounds__(1024)
void loss_kernel(const float* __restrict__ rowsum, const float* __restrict__ sim,
                 float* __restrict__ out, int bn) {
    const int tid  = threadIdx.x;
    const int lane = tid & 63;
    const int wave = tid >> 6;
    float acc = 0.f;
    for (int i = tid; i < bn; i += 1024) acc += logf(rowsum[i]) - sim[i];
#pragma unroll
    for (int off = 1; off < 64; off <<= 1) acc += __shfl_xor(acc, off);
    __shared__ float red[16];
    if (lane == 0) red[wave] = acc;
    __syncthreads();
    if (tid == 0) {
        float t = 0.f;
#pragma unroll
        for (int i = 0; i < 16; i++) t += red[i];
        out[0] = t / (float)bn;
    }
}

extern "C" void kernel_launch(void* const* d_in, const int* in_sizes, int n_in,
                              void* d_out, int out_size, void* d_ws, size_t ws_size,
                              hipStream_t stream) {
    const float* x   = (const float*)d_in[0];
    const float* pos = (const float*)d_in[1];
    const float* neg = (const float*)d_in[2];
    const int bn = in_sizes[0] / DIM;  // 4096
    const int cn = in_sizes[2] / DIM;  // 8192

    // ws layout: Xn fp8 [bn*DIM] | Nn fp8 [cn*DIM] | sim f32 [bn] | rowsum f32 [bn]
    unsigned char* Xn = (unsigned char*)d_ws;
    unsigned char* Nn = Xn + (size_t)bn * DIM;
    float* sim    = (float*)(Nn + (size_t)cn * DIM);
    float* rowsum = sim + bn;

    // opt in to 144 KB dynamic LDS. Host-side attribute set — graph-safe.
    static bool attr_done = false;
    if (!attr_done) {
        (void)hipFuncSetAttribute((const void*)gemm_exp_rowsum,
                                  hipFuncAttributeMaxDynamicSharedMemorySize,
                                  147456);
        attr_done = true;
    }

    prep_all<<<dim3((bn + cn) / 4), dim3(256), 0, stream>>>(x, pos, neg, Xn, Nn, sim, rowsum, bn);
    gemm_exp_rowsum<<<dim3(cn / 128, bn / 256), dim3(512), 147456, stream>>>(Xn, Nn, rowsum);
    loss_kernel<<<dim3(1), dim3(1024), 0, stream>>>(rowsum, sim, (float*)d_out, bn);
}